// Round 8
// baseline (7539.233 us; speedup 1.0000x reference)
//
#include <hip/hip_runtime.h>
#include <stdint.h>

// ---------------------------------------------------------------------------
// GRU encoder (B=128,T=512,D=512,H=512,L=256), MI355X gfx950.
//
// R12 = R11 (real path UNCHANGED: sentinel ring, 64x256, no spills) + two
// ABLATION PROBES on scratch buffers to decompose the 7850cy/step:
//   gru_abl_nowait : WAIT=0 (no sentinel retry), 1536 steps. fill+compute+
//                    store with zero sync stalls. Named kernel -> own row.
//   gru_abl_nofill : WAIT=0, FILL=0 (stale LDS after t=0), 1024 steps.
//                    compute+store core only.
// real step ~ nowait/3 + sync_wait; nowait/3 ~ nofill/2 + fill_cost.
// Probes read real IG (read-only), write scratch ring/hfin. Launched before
// the real gru_rec; correctness unaffected (verified by passed/absmax).
// ---------------------------------------------------------------------------

typedef short short8 __attribute__((ext_vector_type(8)));
typedef float f32x4 __attribute__((ext_vector_type(4)));
typedef int int4v __attribute__((ext_vector_type(4)));

#define NB 128
#define NT 512
#define ND 512
#define NH 512
#define NG 1536   // 3H
#define HSLOT (NB * NH)  // shorts per h ring slot (128 KB)

__device__ __forceinline__ unsigned short f2bf(float f) {
  union { float f; unsigned u; } v; v.f = f;
  unsigned r = v.u + 0x7fffu + ((v.u >> 16) & 1u);  // RNE
  return (unsigned short)(r >> 16);
}
__device__ __forceinline__ float bf2f(unsigned short u) {
  union { unsigned u; float f; } v; v.u = ((unsigned)u) << 16; return v.f;
}
__device__ __forceinline__ float sigmoid_f(float x) {
  float e = __builtin_amdgcn_exp2f(-1.4426950408889634f * x);
  return __builtin_amdgcn_rcpf(1.0f + e);
}
__device__ __forceinline__ float tanh_f(float x) {
  float e = __builtin_amdgcn_exp2f(2.8853900817779268f * x);
  return 1.0f - 2.0f * __builtin_amdgcn_rcpf(1.0f + e);
}
__device__ __forceinline__ short8 pack8(float4 a, float4 b) {
  short8 s;
  s[0] = (short)f2bf(a.x); s[1] = (short)f2bf(a.y);
  s[2] = (short)f2bf(a.z); s[3] = (short)f2bf(a.w);
  s[4] = (short)f2bf(b.x); s[5] = (short)f2bf(b.y);
  s[6] = (short)f2bf(b.z); s[7] = (short)f2bf(b.w);
  return s;
}

__device__ __forceinline__ int4v load16_s(const unsigned short* p) {
  int4v v;
  asm volatile("global_load_dwordx4 %0, %1, off sc0 sc1\n\t"
               "s_waitcnt vmcnt(0)"
               : "=v"(v) : "v"(p) : "memory");
  return v;
}

// four coherent 16B loads + ONE drain (fill path)
__device__ __forceinline__ void load16x4_s(const unsigned short* p0,
                                           const unsigned short* p1,
                                           const unsigned short* p2,
                                           const unsigned short* p3,
                                           int4v* v0, int4v* v1,
                                           int4v* v2, int4v* v3) {
  asm volatile(
      "global_load_dwordx4 %0, %4, off sc0 sc1\n\t"
      "global_load_dwordx4 %1, %5, off sc0 sc1\n\t"
      "global_load_dwordx4 %2, %6, off sc0 sc1\n\t"
      "global_load_dwordx4 %3, %7, off sc0 sc1\n\t"
      "s_waitcnt vmcnt(0)"
      : "=&v"(*v0), "=&v"(*v1), "=&v"(*v2), "=&v"(*v3)
      : "v"(p0), "v"(p1), "v"(p2), "v"(p3) : "memory");
}

// coalesced coherent 8B store, NO drain (ordering via sentinel protocol)
__device__ __forceinline__ void store8_nd(unsigned short* p, unsigned long long v) {
  asm volatile("global_store_dwordx2 %0, %1, off sc0 sc1"
               :: "v"(p), "v"(v) : "memory");
}

__device__ __forceinline__ unsigned pkmax(unsigned a, unsigned b) {
  unsigned d;
  asm("v_pk_max_u16 %0, %1, %2" : "=v"(d) : "v"(a), "v"(b));
  return d;
}
__device__ __forceinline__ bool has_sent(int4v v) {
  unsigned m = pkmax(pkmax((unsigned)v[0], (unsigned)v[1]),
                     pkmax((unsigned)v[2], (unsigned)v[3]));
  return ((m & 0xFFFFu) == 0xFFFFu) || ((m >> 16) == 0xFFFFu);
}

// ---------------------------------------------------------------------------
// IG = x @ Wih^T + bias, bf16 out. (unchanged)
// ---------------------------------------------------------------------------
__global__ __launch_bounds__(256) void ig_gemm(
    const float* __restrict__ x, const float* __restrict__ Wih,
    const float* __restrict__ bias, unsigned short* __restrict__ IG) {
  __shared__ unsigned short As[128 * 40];
  __shared__ unsigned short Bs[128 * 40];
  const int tid = threadIdx.x;
  const int bn = blockIdx.x, bm = blockIdx.y;
  const int lane = tid & 63, w = tid >> 6;
  const int wm = w >> 1, wn = w & 1;
  const int l15 = lane & 15, q = lane >> 4;

  f32x4 acc[4][4] = {};

  for (int kt = 0; kt < 16; ++kt) {
    __syncthreads();
#pragma unroll
    for (int j = 0; j < 4; ++j) {
      int fi = tid + 256 * j;
      int row = fi >> 3, kq = fi & 7;
      float4 v = *(const float4*)(x + (size_t)(bm * 128 + row) * ND + kt * 32 + kq * 4);
      ushort4 s = {f2bf(v.x), f2bf(v.y), f2bf(v.z), f2bf(v.w)};
      *(ushort4*)&As[row * 40 + kq * 4] = s;
    }
#pragma unroll
    for (int j = 0; j < 4; ++j) {
      int fi = tid + 256 * j;
      int row = fi >> 3, kq = fi & 7;
      float4 v = *(const float4*)(Wih + (size_t)(bn * 128 + row) * ND + kt * 32 + kq * 4);
      ushort4 s = {f2bf(v.x), f2bf(v.y), f2bf(v.z), f2bf(v.w)};
      *(ushort4*)&Bs[row * 40 + kq * 4] = s;
    }
    __syncthreads();

    short8 af[4], bf[4];
#pragma unroll
    for (int tm = 0; tm < 4; ++tm)
      af[tm] = *(const short8*)&As[(wm * 64 + tm * 16 + l15) * 40 + q * 8];
#pragma unroll
    for (int tn = 0; tn < 4; ++tn)
      bf[tn] = *(const short8*)&Bs[(wn * 64 + tn * 16 + l15) * 40 + q * 8];
#pragma unroll
    for (int tm = 0; tm < 4; ++tm)
#pragma unroll
      for (int tn = 0; tn < 4; ++tn)
        acc[tm][tn] = __builtin_amdgcn_mfma_f32_16x16x32_bf16(af[tm], bf[tn], acc[tm][tn], 0, 0, 0);
  }

#pragma unroll
  for (int tm = 0; tm < 4; ++tm) {
#pragma unroll
    for (int tn = 0; tn < 4; ++tn) {
      int col = bn * 128 + wn * 64 + tn * 16 + l15;
      float bb = bias[col];
#pragma unroll
      for (int i = 0; i < 4; ++i) {
        int row = bm * 128 + wm * 64 + tm * 16 + q * 4 + i;
        IG[(size_t)row * NG + col] = f2bf(acc[tm][tn][i] + bb);
      }
    }
  }
}

// ---------------------------------------------------------------------------
// Shared GRU recurrence core (R11 body, parameterized).
// WAIT: sentinel retry on peer loads. FILL: global fill after t=0.
// ---------------------------------------------------------------------------
template <bool USE_IG, bool WAIT, bool FILL>
__device__ __forceinline__ void gru_core(
    int nsteps, const float* __restrict__ x, const float* __restrict__ Wih,
    const float* __restrict__ Whh, const float* __restrict__ bias,
    const float* __restrict__ bn, const unsigned short* __restrict__ IG,
    unsigned short* __restrict__ hbuf, float* __restrict__ hfin,
    unsigned short* hs, unsigned short* ts) {
  const int tid = threadIdx.x;
  const int lane = tid & 63;
  const int w = tid >> 6;                  // 0..3
  const int l15 = lane & 15, q = lane >> 4;
  const int bid = blockIdx.x;
  const int g = bid & 7, c = bid >> 3;
  const int col = c * 64 + w * 16 + l15;
  const int erow = g * 16 + q * 4;
  const int mrow = g * 16 + l15;

  short8 bfr[3][16];
#pragma unroll
  for (int gt = 0; gt < 3; ++gt) {
    const float* src = Whh + (size_t)(gt * NH + col) * NH + q * 8;
#pragma unroll
    for (int kk = 0; kk < 16; ++kk) {
      float4 v0 = *(const float4*)(src + kk * 32);
      float4 v1 = *(const float4*)(src + kk * 32 + 4);
      bfr[gt][kk] = pack8(v0, v1);
    }
  }

  float bi_r = 0.f, bi_z = 0.f, bi_n = 0.f;
  if (!USE_IG) {
    bi_r = bias[col];
    bi_z = bias[NH + col];
    bi_n = bias[2 * NH + col];
  }
  const float bnv = bn[col];

  float hreg[4] = {0.f, 0.f, 0.f, 0.f};

  const int frow = tid >> 4;
  const int fg0 = (tid & 15) * 4;
  const int fr7 = frow & 7;
  const bool own_slot = ((fg0 >> 3) == c);

  const int srow = tid >> 4;
  const int scol = (tid & 15) * 4;
  const size_t cell_off = (size_t)(g * 16 + srow) * NH + c * 64 + scol;

  for (int t = 0; t < nsteps; ++t) {
    const int tig = t & (NT - 1);
    const unsigned short* hcur = hbuf + (size_t)(t & 3) * HSLOT;
    unsigned short* hnxt  = hbuf + (size_t)((t + 1) & 3) * HSLOT;
    unsigned short* hsent = hbuf + (size_t)((t + 2) & 3) * HSLOT;

    float igr[4], igz[4], ign[4];
    if (USE_IG) {
#pragma unroll
      for (int i = 0; i < 4; ++i) {
        const size_t base = ((size_t)(erow + i) * NT + tig) * NG + col;
        igr[i] = bf2f(IG[base]);
        igz[i] = bf2f(IG[base + NH]);
        ign[i] = bf2f(IG[base + 2 * NH]);
      }
    }

    if (t > 0 && own_slot) {
#pragma unroll
      for (int j = 0; j < 4; ++j) {
        const int s = fg0 + j;
        const int ls = (s ^ fr7) & 7;
        *(int4v*)&hs[frow * 512 + (s << 3)] =
            *(const int4v*)&ts[frow * 64 + ls * 8];
      }
    } else if (FILL || t == 0) {
      const unsigned short* hrow = hcur + (size_t)(g * 16 + frow) * NH;
      const unsigned short* p0 = hrow + (((fg0 + 0) ^ fr7) << 3);
      const unsigned short* p1 = hrow + (((fg0 + 1) ^ fr7) << 3);
      const unsigned short* p2 = hrow + (((fg0 + 2) ^ fr7) << 3);
      const unsigned short* p3 = hrow + (((fg0 + 3) ^ fr7) << 3);
      int4v v0, v1, v2, v3;
      load16x4_s(p0, p1, p2, p3, &v0, &v1, &v2, &v3);
      if (WAIT && t > 0) {
        while (has_sent(v0)) v0 = load16_s(p0);
        while (has_sent(v1)) v1 = load16_s(p1);
        while (has_sent(v2)) v2 = load16_s(p2);
        while (has_sent(v3)) v3 = load16_s(p3);
      }
      *(int4v*)&hs[frow * 512 + ((fg0 + 0) << 3)] = v0;
      *(int4v*)&hs[frow * 512 + ((fg0 + 1) << 3)] = v1;
      *(int4v*)&hs[frow * 512 + ((fg0 + 2) << 3)] = v2;
      *(int4v*)&hs[frow * 512 + ((fg0 + 3) << 3)] = v3;
    }
    __syncthreads();

    if (t + 2 < nsteps) {
      store8_nd(hsent + cell_off, 0xFFFFFFFFFFFFFFFFull);
    }

    f32x4 ar = {0.f, 0.f, 0.f, 0.f};
    f32x4 az = {0.f, 0.f, 0.f, 0.f};
    f32x4 an = {0.f, 0.f, 0.f, 0.f};
    f32x4 ai = {0.f, 0.f, 0.f, 0.f};
    const int abase = l15 * 512;
    const int ar7 = (l15 & 7) << 3;
#pragma unroll
    for (int kk = 0; kk < 16; ++kk) {
      short8 afk = *(const short8*)&hs[abase + ((kk * 32 + q * 8) ^ ar7)];
      ar = __builtin_amdgcn_mfma_f32_16x16x32_bf16(afk, bfr[0][kk], ar, 0, 0, 0);
      az = __builtin_amdgcn_mfma_f32_16x16x32_bf16(afk, bfr[1][kk], az, 0, 0, 0);
      an = __builtin_amdgcn_mfma_f32_16x16x32_bf16(afk, bfr[2][kk], an, 0, 0, 0);
      if (!USE_IG) {
        const float* xp = x + ((size_t)mrow * NT + tig) * ND + kk * 32 + q * 8;
        short8 xa = pack8(*(const float4*)xp, *(const float4*)(xp + 4));
#pragma unroll
        for (int gt = 0; gt < 3; ++gt) {
          const float* wp = Wih + (size_t)(gt * NH + col) * ND + kk * 32 + q * 8;
          short8 wf = pack8(*(const float4*)wp, *(const float4*)(wp + 4));
          if (gt == 0) ar = __builtin_amdgcn_mfma_f32_16x16x32_bf16(xa, wf, ar, 0, 0, 0);
          if (gt == 1) az = __builtin_amdgcn_mfma_f32_16x16x32_bf16(xa, wf, az, 0, 0, 0);
          if (gt == 2) ai = __builtin_amdgcn_mfma_f32_16x16x32_bf16(xa, wf, ai, 0, 0, 0);
        }
      }
    }

    unsigned short sv[4];
#pragma unroll
    for (int i = 0; i < 4; ++i) {
      float xr = USE_IG ? (ar[i] + igr[i]) : (ar[i] + bi_r);
      float xz = USE_IG ? (az[i] + igz[i]) : (az[i] + bi_z);
      float xin = USE_IG ? ign[i] : (ai[i] + bi_n);
      float r = sigmoid_f(xr);
      float z = sigmoid_f(xz);
      float n = tanh_f(xin + r * (an[i] + bnv));
      float hn2 = (1.f - z) * n + z * hreg[i];
      hreg[i] = hn2;
      sv[i] = f2bf(hn2);
      if (t == nsteps - 1) hfin[(size_t)(erow + i) * NH + col] = hn2;
    }

    if (t != nsteps - 1) {
#pragma unroll
      for (int i = 0; i < 4; ++i)
        ts[(q * 4 + i) * 64 + w * 16 + l15] = sv[i];
      asm volatile("s_waitcnt vmcnt(0)" ::: "memory");
      __syncthreads();
      unsigned long long v8 = *(const unsigned long long*)&ts[srow * 64 + scol];
      store8_nd(hnxt + cell_off, v8);
    }
  }
}

// real kernel (R11 behavior, unchanged)
template <bool USE_IG>
__global__ __launch_bounds__(256, 1) void gru_rec(
    const float* __restrict__ x, const float* __restrict__ Wih,
    const float* __restrict__ Whh, const float* __restrict__ bias,
    const float* __restrict__ bn, const unsigned short* __restrict__ IG,
    unsigned short* __restrict__ hbuf, float* __restrict__ hfin) {
  __shared__ unsigned short hs[16 * 512];
  __shared__ unsigned short ts[16 * 64];
  gru_core<USE_IG, true, true>(NT, x, Wih, Whh, bias, bn, IG, hbuf, hfin, hs, ts);
}

// probe 1: no sentinel wait, 3x steps (scratch buffers)
__global__ __launch_bounds__(256, 1) void gru_abl_nowait(
    const float* __restrict__ x, const float* __restrict__ Wih,
    const float* __restrict__ Whh, const float* __restrict__ bias,
    const float* __restrict__ bn, const unsigned short* __restrict__ IG,
    unsigned short* __restrict__ hbuf, float* __restrict__ hfin) {
  __shared__ unsigned short hs[16 * 512];
  __shared__ unsigned short ts[16 * 64];
  gru_core<true, false, true>(3 * NT, x, Wih, Whh, bias, bn, IG, hbuf, hfin, hs, ts);
}

// probe 2: no wait + no global fill after t=0, 2x steps (scratch buffers)
__global__ __launch_bounds__(256, 1) void gru_abl_nofill(
    const float* __restrict__ x, const float* __restrict__ Wih,
    const float* __restrict__ Whh, const float* __restrict__ bias,
    const float* __restrict__ bn, const unsigned short* __restrict__ IG,
    unsigned short* __restrict__ hbuf, float* __restrict__ hfin) {
  __shared__ unsigned short hs[16 * 512];
  __shared__ unsigned short ts[16 * 64];
  gru_core<true, false, false>(2 * NT, x, Wih, Whh, bias, bn, IG, hbuf, hfin, hs, ts);
}

// ---------------------------------------------------------------------------
// out = h_T @ Wlin^T + blin (unchanged)
// ---------------------------------------------------------------------------
__global__ __launch_bounds__(256) void final_linear(
    const float* __restrict__ hfin, const float* __restrict__ Wlin,
    const float* __restrict__ blin, float* __restrict__ out) {
  __shared__ float sh[16 * 516];
  const int tid = threadIdx.x;
  const int b0 = blockIdx.y * 16, o0 = blockIdx.x * 16;

  for (int j = tid; j < 16 * 128; j += 256) {
    int row = j >> 7, kq = j & 127;
    *(float4*)&sh[row * 516 + kq * 4] =
        *(const float4*)(hfin + (size_t)(b0 + row) * NH + kq * 4);
  }
  __syncthreads();

  const int bi = tid & 15, oi = tid >> 4;
  const int o = o0 + oi;
  const float4* wp = (const float4*)(Wlin + (size_t)o * NH);
  float4 a4 = {0.f, 0.f, 0.f, 0.f};
  for (int k4 = 0; k4 < 128; ++k4) {
    float4 wv = wp[k4];
    float4 hv = *(const float4*)&sh[bi * 516 + k4 * 4];
    a4.x += wv.x * hv.x; a4.y += wv.y * hv.y;
    a4.z += wv.z * hv.z; a4.w += wv.w * hv.w;
  }
  float v = a4.x + a4.y + a4.z + a4.w + blin[o];
  int b = b0 + bi;
  if (o < 256) out[b * 256 + o] = v;
  else out[32768 + b * 256 + (o - 256)] = v;
}

// ---------------------------------------------------------------------------
extern "C" void kernel_launch(void* const* d_in, const int* in_sizes, int n_in,
                              void* d_out, int out_size, void* d_ws, size_t ws_size,
                              hipStream_t stream) {
  const float* x    = (const float*)d_in[0];
  const float* Wih  = (const float*)d_in[1];
  const float* Whh  = (const float*)d_in[2];
  const float* bias = (const float*)d_in[3];
  const float* bn   = (const float*)d_in[4];
  const float* Wlin = (const float*)d_in[5];
  const float* blin = (const float*)d_in[6];
  float* out = (float*)d_out;

  char* ws = (char*)d_ws;
  // layout: [h ring 524288][hfin 262144][IG 201326592][abl ring 524288][abl hfin 262144]
  unsigned short* hbuf = (unsigned short*)ws;
  float* hfin          = (float*)(ws + 4 * 131072);
  unsigned short* IG   = (unsigned short*)(ws + 4 * 131072 + 262144);
  const size_t need_min = 4 * 131072 + 262144;                  // 786432
  const size_t need_ig  = need_min + (size_t)NB * NT * NG * 2;  // ~202 MB
  const size_t need_abl = need_ig + 786432;
  unsigned short* hbuf2 = (unsigned short*)(ws + need_ig);
  float* hfin2          = (float*)(ws + need_ig + 4 * 131072);
  if (ws_size < need_min) return;

  // slot0 = h_0 = 0; slots 1..3 = 0xFFFF sentinel (graph-capture-safe)
  hipMemsetAsync(ws, 0, 131072, stream);
  hipMemsetAsync(ws + 131072, 0xFF, 3 * 131072, stream);

  const bool useIG = (ws_size >= need_ig);
  const bool doAbl = (ws_size >= need_abl);
  if (useIG) {
    ig_gemm<<<dim3(12, 512), 256, 0, stream>>>(x, Wih, bias, IG);
    if (doAbl) {
      hipMemsetAsync((char*)hbuf2, 0, 131072, stream);
      hipMemsetAsync((char*)hbuf2 + 131072, 0xFF, 3 * 131072, stream);
      gru_abl_nowait<<<64, 256, 0, stream>>>(x, Wih, Whh, bias, bn, IG, hbuf2, hfin2);
      gru_abl_nofill<<<64, 256, 0, stream>>>(x, Wih, Whh, bias, bn, IG, hbuf2, hfin2);
    }
    gru_rec<true><<<64, 256, 0, stream>>>(x, Wih, Whh, bias, bn, IG, hbuf, hfin);
  } else {
    gru_rec<false><<<64, 256, 0, stream>>>(x, Wih, Whh, bias, bn, nullptr, hbuf, hfin);
  }
  final_linear<<<dim3(32, 8), 256, 0, stream>>>(hfin, Wlin, blin, out);
}

// Round 9
// 2261.449 us; speedup vs baseline: 3.3338x; 3.3338x over previous
//
#include <hip/hip_runtime.h>
#include <stdint.h>

// ---------------------------------------------------------------------------
// GRU encoder (B=128,T=512,D=512,H=512,L=256), MI355X gfx950.
//
// R13: ablation (R12) showed step = core 1.52us + fill 1.03us + wait 0.72us,
// all SERIAL (1 wave/SIMD, nothing overlaps). This round overlaps them via
// batch-group ALTERNATION on the proven R11 body (256-thr blocks, no spill):
//   32 blocks x 256 thr. block = (pair p: row groups A=32p..+16, B=+16) x
//   (col chunk c of 64). bfr (Whh fragments, 192 VGPR) shared by A and B.
//   Phase X of step t: [retry-check prefetched X(t) granules] -> LDS ->
//   barrier -> sentinelX(t+2) + ISSUE other group's granule loads ->
//   MFMA/gates (covers their latency) -> transpose -> vmcnt(0) pass-through
//   (orders prefetch completion) -> barrier -> store h_{t+1}(X rows).
//   Peer's storeX(t) lands a full opposite-phase (~1500cy) before my
//   check -> wait ~0, fill RTT hidden.
// Changes vs R11 data path:
//   - own-slot LDS copy DROPPED: all granules from global (own data is
//     visible to self: stored >1 phase ago with vmcnt(0) drains between).
//   - fill granules STRIDED (thread takes s = k15+16j, j=0..3) -> LDS write
//     conflicts 8-way -> 2-way (free). hs layout unchanged: granule s holds
//     global granule s^(row&7); compute reads verbatim.
// Protocol: R9/R11 sentinel ring verbatim per group (rows disjoint):
//   ordering: sentinelX(t+2) drained (end-of-phase vmcnt(0)) before
//   storeX(h_{t+1}) issued => anyone observing h_{t+1}(X) sees sentinel
//   first; slot t+2 read as h_{t+2} only in phase X(t+2), later.
//   readers-done: my fillX(t) success => peers stored h_t(X) (their phase
//   X(t-1)) => they completed fillX(t-1) => a fortiori fillX(t-2) reads of
//   h_{t-2}(X) (the slot being sentinel'd) are done. R=4 ring.
//   deadlock-free: X spinning at A(t) has already stored everything through
//   B(t-1); peers need nothing newer to finish A(t-1)'s store.
// ---------------------------------------------------------------------------

typedef short short8 __attribute__((ext_vector_type(8)));
typedef float f32x4 __attribute__((ext_vector_type(4)));
typedef int int4v __attribute__((ext_vector_type(4)));

#define NB 128
#define NT 512
#define ND 512
#define NH 512
#define NG 1536   // 3H
#define HSLOT (NB * NH)  // shorts per h ring slot (128 KB)

__device__ __forceinline__ unsigned short f2bf(float f) {
  union { float f; unsigned u; } v; v.f = f;
  unsigned r = v.u + 0x7fffu + ((v.u >> 16) & 1u);  // RNE
  return (unsigned short)(r >> 16);
}
__device__ __forceinline__ float bf2f(unsigned short u) {
  union { unsigned u; float f; } v; v.u = ((unsigned)u) << 16; return v.f;
}
__device__ __forceinline__ float sigmoid_f(float x) {
  float e = __builtin_amdgcn_exp2f(-1.4426950408889634f * x);
  return __builtin_amdgcn_rcpf(1.0f + e);
}
__device__ __forceinline__ float tanh_f(float x) {
  float e = __builtin_amdgcn_exp2f(2.8853900817779268f * x);
  return 1.0f - 2.0f * __builtin_amdgcn_rcpf(1.0f + e);
}
__device__ __forceinline__ short8 pack8(float4 a, float4 b) {
  short8 s;
  s[0] = (short)f2bf(a.x); s[1] = (short)f2bf(a.y);
  s[2] = (short)f2bf(a.z); s[3] = (short)f2bf(a.w);
  s[4] = (short)f2bf(b.x); s[5] = (short)f2bf(b.y);
  s[6] = (short)f2bf(b.z); s[7] = (short)f2bf(b.w);
  return s;
}

// issue 4 coherent 16B loads at p, p+256B, p+512B, p+768B -- NO wait.
// Consumers must be ordered behind a pass-through s_waitcnt (wait4).
__device__ __forceinline__ void issue16x4(const unsigned short* p, int4v (&v)[4]) {
  asm volatile(
      "global_load_dwordx4 %0, %4, off sc0 sc1\n\t"
      "global_load_dwordx4 %1, %4, off offset:256 sc0 sc1\n\t"
      "global_load_dwordx4 %2, %4, off offset:512 sc0 sc1\n\t"
      "global_load_dwordx4 %3, %4, off offset:768 sc0 sc1"
      : "=&v"(v[0]), "=&v"(v[1]), "=&v"(v[2]), "=&v"(v[3])
      : "v"(p) : "memory");
}

// drain all vmem; v passed through as in/out so any later use of v is
// data-ordered after the wait (robust against hoisting, rule #18).
__device__ __forceinline__ void wait4(int4v (&v)[4]) {
  asm volatile("s_waitcnt vmcnt(0)"
               : "+v"(v[0]), "+v"(v[1]), "+v"(v[2]), "+v"(v[3]) :: "memory");
}

__device__ __forceinline__ int4v load16_s(const unsigned short* p) {
  int4v v;
  asm volatile("global_load_dwordx4 %0, %1, off sc0 sc1\n\t"
               "s_waitcnt vmcnt(0)"
               : "=v"(v) : "v"(p) : "memory");
  return v;
}

// coalesced coherent 8B store, NO drain (ordering via sentinel protocol)
__device__ __forceinline__ void store8_nd(unsigned short* p, unsigned long long v) {
  asm volatile("global_store_dwordx2 %0, %1, off sc0 sc1"
               :: "v"(p), "v"(v) : "memory");
}

__device__ __forceinline__ unsigned pkmax(unsigned a, unsigned b) {
  unsigned d;
  asm("v_pk_max_u16 %0, %1, %2" : "=v"(d) : "v"(a), "v"(b));
  return d;
}
__device__ __forceinline__ bool has_sent(int4v v) {
  unsigned m = pkmax(pkmax((unsigned)v[0], (unsigned)v[1]),
                     pkmax((unsigned)v[2], (unsigned)v[3]));
  return ((m & 0xFFFFu) == 0xFFFFu) || ((m >> 16) == 0xFFFFu);
}

// ---------------------------------------------------------------------------
// IG = x @ Wih^T + bias, bf16 out. (unchanged)
// ---------------------------------------------------------------------------
__global__ __launch_bounds__(256) void ig_gemm(
    const float* __restrict__ x, const float* __restrict__ Wih,
    const float* __restrict__ bias, unsigned short* __restrict__ IG) {
  __shared__ unsigned short As[128 * 40];
  __shared__ unsigned short Bs[128 * 40];
  const int tid = threadIdx.x;
  const int bn = blockIdx.x, bm = blockIdx.y;
  const int lane = tid & 63, w = tid >> 6;
  const int wm = w >> 1, wn = w & 1;
  const int l15 = lane & 15, q = lane >> 4;

  f32x4 acc[4][4] = {};

  for (int kt = 0; kt < 16; ++kt) {
    __syncthreads();
#pragma unroll
    for (int j = 0; j < 4; ++j) {
      int fi = tid + 256 * j;
      int row = fi >> 3, kq = fi & 7;
      float4 v = *(const float4*)(x + (size_t)(bm * 128 + row) * ND + kt * 32 + kq * 4);
      ushort4 s = {f2bf(v.x), f2bf(v.y), f2bf(v.z), f2bf(v.w)};
      *(ushort4*)&As[row * 40 + kq * 4] = s;
    }
#pragma unroll
    for (int j = 0; j < 4; ++j) {
      int fi = tid + 256 * j;
      int row = fi >> 3, kq = fi & 7;
      float4 v = *(const float4*)(Wih + (size_t)(bn * 128 + row) * ND + kt * 32 + kq * 4);
      ushort4 s = {f2bf(v.x), f2bf(v.y), f2bf(v.z), f2bf(v.w)};
      *(ushort4*)&Bs[row * 40 + kq * 4] = s;
    }
    __syncthreads();

    short8 af[4], bf[4];
#pragma unroll
    for (int tm = 0; tm < 4; ++tm)
      af[tm] = *(const short8*)&As[(wm * 64 + tm * 16 + l15) * 40 + q * 8];
#pragma unroll
    for (int tn = 0; tn < 4; ++tn)
      bf[tn] = *(const short8*)&Bs[(wn * 64 + tn * 16 + l15) * 40 + q * 8];
#pragma unroll
    for (int tm = 0; tm < 4; ++tm)
#pragma unroll
      for (int tn = 0; tn < 4; ++tn)
        acc[tm][tn] = __builtin_amdgcn_mfma_f32_16x16x32_bf16(af[tm], bf[tn], acc[tm][tn], 0, 0, 0);
  }

#pragma unroll
  for (int tm = 0; tm < 4; ++tm) {
#pragma unroll
    for (int tn = 0; tn < 4; ++tn) {
      int col = bn * 128 + wn * 64 + tn * 16 + l15;
      float bb = bias[col];
#pragma unroll
      for (int i = 0; i < 4; ++i) {
        int row = bm * 128 + wm * 64 + tm * 16 + q * 4 + i;
        IG[(size_t)row * NG + col] = f2bf(acc[tm][tn][i] + bb);
      }
    }
  }
}

// ---------------------------------------------------------------------------
// One group-phase of the GRU step: 16 rows (rbase..+16) x 512 cols -> this
// block's 64-col slice of h_{t+1}. Prefetch of the NEXT phase's granules is
// issued mid-phase and completed by the end-of-phase wait4.
// ---------------------------------------------------------------------------
template <bool USE_IG>
__device__ __forceinline__ void gru_phase(
    int t, int rbase, unsigned short* __restrict__ ts,
    int t_nxt, int rbase_nxt, bool issue_nxt,
    int4v (&v)[4],
    const float* __restrict__ x, const float* __restrict__ Wih,
    const unsigned short* __restrict__ IG,
    unsigned short* __restrict__ hbuf, float* __restrict__ hfin,
    unsigned short* __restrict__ hs,
    const short8 (&bfr)[3][16], float (&hreg)[4],
    float bi_r, float bi_z, float bi_n, float bnv,
    int tid, int w, int l15, int q, int c) {
  const int col = c * 64 + w * 16 + l15;
  const int erow = rbase + q * 4;
  const int mrow = rbase + l15;

  const int frow = tid >> 4;          // 0..15
  const int k15 = tid & 15;
  const int fr7 = frow & 7;
  const int gbase = (k15 ^ fr7) << 3; // element offset of granule j=0 (swizzled)

  const int srow = frow;
  const int scol = k15 * 4;           // shorts
  const size_t cell_off = (size_t)(rbase + srow) * NH + c * 64 + scol;

  // IG loads (plain cached; latency overlaps fill/compute)
  float igr[4], igz[4], ign[4];
  if (USE_IG) {
#pragma unroll
    for (int i = 0; i < 4; ++i) {
      const size_t base = ((size_t)(erow + i) * NT + t) * NG + col;
      igr[i] = bf2f(IG[base]);
      igz[i] = bf2f(IG[base + NH]);
      ign[i] = bf2f(IG[base + 2 * NH]);
    }
  }

  // fill: prefetched granules (s = k15+16j; hs granule s holds global
  // granule s^fr7; strided -> 2-way LDS write aliasing only)
  {
    const unsigned short* hrow =
        hbuf + (size_t)(t & 3) * HSLOT + (size_t)(rbase + frow) * NH;
    if (t > 0) {
#pragma unroll
      for (int j = 0; j < 4; ++j)
        while (has_sent(v[j])) v[j] = load16_s(hrow + gbase + j * 128);
    }
#pragma unroll
    for (int j = 0; j < 4; ++j)
      *(int4v*)&hs[frow * 512 + k15 * 8 + j * 128] = v[j];
  }
  __syncthreads();

  // sentinel slot t+2 at own cell; then issue next phase's granule loads
  // (their latency hides under the MFMA loop; completed by wait4 below).
  if (t + 2 < NT)
    store8_nd(hbuf + (size_t)((t + 2) & 3) * HSLOT + cell_off,
              0xFFFFFFFFFFFFFFFFull);
  if (issue_nxt) {
    const unsigned short* hrow_n =
        hbuf + (size_t)(t_nxt & 3) * HSLOT + (size_t)(rbase_nxt + frow) * NH;
    issue16x4(hrow_n + gbase, v);
  }

  f32x4 ar = {0.f, 0.f, 0.f, 0.f};
  f32x4 az = {0.f, 0.f, 0.f, 0.f};
  f32x4 an = {0.f, 0.f, 0.f, 0.f};
  f32x4 ai = {0.f, 0.f, 0.f, 0.f};
  const int abase = l15 * 512;
  const int ar7 = (l15 & 7) << 3;
#pragma unroll
  for (int kk = 0; kk < 16; ++kk) {
    short8 afk = *(const short8*)&hs[abase + ((kk * 32 + q * 8) ^ ar7)];
    ar = __builtin_amdgcn_mfma_f32_16x16x32_bf16(afk, bfr[0][kk], ar, 0, 0, 0);
    az = __builtin_amdgcn_mfma_f32_16x16x32_bf16(afk, bfr[1][kk], az, 0, 0, 0);
    an = __builtin_amdgcn_mfma_f32_16x16x32_bf16(afk, bfr[2][kk], an, 0, 0, 0);
    if (!USE_IG) {
      const float* xp = x + ((size_t)mrow * NT + t) * ND + kk * 32 + q * 8;
      short8 xa = pack8(*(const float4*)xp, *(const float4*)(xp + 4));
#pragma unroll
      for (int gt = 0; gt < 3; ++gt) {
        const float* wp = Wih + (size_t)(gt * NH + col) * ND + kk * 32 + q * 8;
        short8 wf = pack8(*(const float4*)wp, *(const float4*)(wp + 4));
        if (gt == 0) ar = __builtin_amdgcn_mfma_f32_16x16x32_bf16(xa, wf, ar, 0, 0, 0);
        if (gt == 1) az = __builtin_amdgcn_mfma_f32_16x16x32_bf16(xa, wf, az, 0, 0, 0);
        if (gt == 2) ai = __builtin_amdgcn_mfma_f32_16x16x32_bf16(xa, wf, ai, 0, 0, 0);
      }
    }
  }

  // gates + h update
  unsigned short sv[4];
#pragma unroll
  for (int i = 0; i < 4; ++i) {
    float xr = USE_IG ? (ar[i] + igr[i]) : (ar[i] + bi_r);
    float xz = USE_IG ? (az[i] + igz[i]) : (az[i] + bi_z);
    float xin = USE_IG ? ign[i] : (ai[i] + bi_n);
    float r = sigmoid_f(xr);
    float z = sigmoid_f(xz);
    float n = tanh_f(xin + r * (an[i] + bnv));
    float hn2 = (1.f - z) * n + z * hreg[i];
    hreg[i] = hn2;
    sv[i] = f2bf(hn2);
    if (t == NT - 1) hfin[(size_t)(erow + i) * NH + col] = hn2;
  }

  if (t != NT - 1) {
    // transpose C-layout -> row-major 16x64 tile in ts
#pragma unroll
    for (int i = 0; i < 4; ++i)
      ts[(q * 4 + i) * 64 + w * 16 + l15] = sv[i];
    // drain: sentinel visible + prefetched granules complete (pass-through
    // orders next phase's reads of v after this wait). Then barrier: all
    // sentinels visible + hs reads/ts writes done before ANY data store.
    wait4(v);
    __syncthreads();
    store8_nd(hbuf + (size_t)((t + 1) & 3) * HSLOT + cell_off,
              *(const unsigned long long*)&ts[srow * 64 + scol]);
  } else {
    wait4(v);          // complete prefetch for the following phase (if any)
    __syncthreads();   // protect hs
  }
}

// ---------------------------------------------------------------------------
// Persistent GRU recurrence. 32 blocks x 256 threads (4 waves, 1/SIMD).
// block: p = bid>>3 (pair: rows A=32p..+16, B=32p+16..+16), c = bid&7
// (cols c*64..+64). Community = 8 col-chunk blocks of pair p per group.
// ---------------------------------------------------------------------------
template <bool USE_IG>
__global__ __launch_bounds__(256, 1) void gru_rec(
    const float* __restrict__ x, const float* __restrict__ Wih,
    const float* __restrict__ Whh, const float* __restrict__ bias,
    const float* __restrict__ bn, const unsigned short* __restrict__ IG,
    unsigned short* __restrict__ hbuf, float* __restrict__ hfin) {
  __shared__ __align__(16) unsigned short hs[16 * 512];  // 16 KB slab
  __shared__ __align__(16) unsigned short tsA[16 * 64];  // 2 KB store tiles
  __shared__ __align__(16) unsigned short tsB[16 * 64];

  const int tid = threadIdx.x;
  const int lane = tid & 63;
  const int w = tid >> 6;                  // 0..3
  const int l15 = lane & 15, q = lane >> 4;
  const int bid = blockIdx.x;
  const int p = bid >> 3, c = bid & 7;
  const int rbA = p * 32, rbB = p * 32 + 16;
  const int col = c * 64 + w * 16 + l15;

  // Whh B-fragments (shared by groups A and B): 192 VGPRs, no spill at
  // 1 wave/EU (512-reg budget).
  short8 bfr[3][16];
#pragma unroll
  for (int gt = 0; gt < 3; ++gt) {
    const float* src = Whh + (size_t)(gt * NH + col) * NH + q * 8;
#pragma unroll
    for (int kk = 0; kk < 16; ++kk) {
      float4 v0 = *(const float4*)(src + kk * 32);
      float4 v1 = *(const float4*)(src + kk * 32 + 4);
      bfr[gt][kk] = pack8(v0, v1);
    }
  }

  float bi_r = 0.f, bi_z = 0.f, bi_n = 0.f;
  if (!USE_IG) {
    bi_r = bias[col];
    bi_z = bias[NH + col];
    bi_n = bias[2 * NH + col];
  }
  const float bnv = bn[col];

  float hregA[4] = {0.f, 0.f, 0.f, 0.f};
  float hregB[4] = {0.f, 0.f, 0.f, 0.f};

  // prologue: load A(0) granules from slot 0 (pre-zeroed = h_0)
  int4v v[4];
  {
    const int frow = tid >> 4, k15 = tid & 15, fr7 = frow & 7;
    const unsigned short* hrow = hbuf + (size_t)(rbA + frow) * NH;
    issue16x4(hrow + ((k15 ^ fr7) << 3), v);
    wait4(v);
  }

  for (int t = 0; t < NT; ++t) {
    gru_phase<USE_IG>(t, rbA, tsA, t, rbB, true, v, x, Wih, IG, hbuf, hfin,
                      hs, bfr, hregA, bi_r, bi_z, bi_n, bnv, tid, w, l15, q, c);
    gru_phase<USE_IG>(t, rbB, tsB, t + 1, rbA, (t + 1) < NT, v, x, Wih, IG,
                      hbuf, hfin, hs, bfr, hregB, bi_r, bi_z, bi_n, bnv,
                      tid, w, l15, q, c);
  }
}

// ---------------------------------------------------------------------------
// out = h_T @ Wlin^T + blin (unchanged)
// ---------------------------------------------------------------------------
__global__ __launch_bounds__(256) void final_linear(
    const float* __restrict__ hfin, const float* __restrict__ Wlin,
    const float* __restrict__ blin, float* __restrict__ out) {
  __shared__ float sh[16 * 516];
  const int tid = threadIdx.x;
  const int b0 = blockIdx.y * 16, o0 = blockIdx.x * 16;

  for (int j = tid; j < 16 * 128; j += 256) {
    int row = j >> 7, kq = j & 127;
    *(float4*)&sh[row * 516 + kq * 4] =
        *(const float4*)(hfin + (size_t)(b0 + row) * NH + kq * 4);
  }
  __syncthreads();

  const int bi = tid & 15, oi = tid >> 4;
  const int o = o0 + oi;
  const float4* wp = (const float4*)(Wlin + (size_t)o * NH);
  float4 a4 = {0.f, 0.f, 0.f, 0.f};
  for (int k4 = 0; k4 < 128; ++k4) {
    float4 wv = wp[k4];
    float4 hv = *(const float4*)&sh[bi * 516 + k4 * 4];
    a4.x += wv.x * hv.x; a4.y += wv.y * hv.y;
    a4.z += wv.z * hv.z; a4.w += wv.w * hv.w;
  }
  float v = a4.x + a4.y + a4.z + a4.w + blin[o];
  int b = b0 + bi;
  if (o < 256) out[b * 256 + o] = v;
  else out[32768 + b * 256 + (o - 256)] = v;
}

// ---------------------------------------------------------------------------
extern "C" void kernel_launch(void* const* d_in, const int* in_sizes, int n_in,
                              void* d_out, int out_size, void* d_ws, size_t ws_size,
                              hipStream_t stream) {
  const float* x    = (const float*)d_in[0];
  const float* Wih  = (const float*)d_in[1];
  const float* Whh  = (const float*)d_in[2];
  const float* bias = (const float*)d_in[3];
  const float* bn   = (const float*)d_in[4];
  const float* Wlin = (const float*)d_in[5];
  const float* blin = (const float*)d_in[6];
  float* out = (float*)d_out;

  char* ws = (char*)d_ws;
  // layout: [h ring 4*131072][hfin 262144][IG 201326592]
  unsigned short* hbuf = (unsigned short*)ws;
  float* hfin          = (float*)(ws + 4 * 131072);
  unsigned short* IG   = (unsigned short*)(ws + 4 * 131072 + 262144);
  const size_t need_min = 4 * 131072 + 262144;                  // 786432
  const size_t need_ig  = need_min + (size_t)NB * NT * NG * 2;  // ~202 MB
  if (ws_size < need_min) return;

  // slot0 = h_0 = 0; slots 1..3 = 0xFFFF sentinel (graph-capture-safe)
  hipMemsetAsync(ws, 0, 131072, stream);
  hipMemsetAsync(ws + 131072, 0xFF, 3 * 131072, stream);

  const bool useIG = (ws_size >= need_ig);
  if (useIG) {
    ig_gemm<<<dim3(12, 512), 256, 0, stream>>>(x, Wih, bias, IG);
    gru_rec<true><<<32, 256, 0, stream>>>(x, Wih, Whh, bias, bn, IG, hbuf, hfin);
  } else {
    gru_rec<false><<<32, 256, 0, stream>>>(x, Wih, Whh, bias, bn, nullptr, hbuf, hfin);
  }
  final_linear<<<dim3(32, 8), 256, 0, stream>>>(hfin, Wlin, blin, out);
}

// Round 12
// 2059.902 us; speedup vs baseline: 3.6600x; 1.0978x over previous
//
#include <hip/hip_runtime.h>
#include <stdint.h>

// ---------------------------------------------------------------------------
// GRU encoder (B=128,T=512,D=512,H=512,L=256), MI355X gfx950.
//
// R16 = R11 (PROVEN best passing: sentinel ring, 64 blocks x 256 thr, LDS
// slab, 2 barriers, sentinel AFTER FULL validation) + exactly three
// R13-proven ingredients:
//   1) prefetch-as-poll: next step's 4 granules issued at end of step t
//      (R13 phase-B->A(t+1) pattern, passed). Head-of-step wait = drain.
//   2) strided fill: thread owns granules {j2, j2+16, 32+j2, 48+j2} ->
//      LDS write conflicts 8-way -> 2-way (R13 pattern, passed).
//   3) no own-slot ts copy: all granules from global; load-vs-own-store
//      race returns sentinel at worst, retry fixes (R13, passed).
// Protocol placement unchanged from R11 (empirical rule from 12 rounds:
// sentinel only after FULL h_t validation + barrier; early/unbarriered
// variants all failed): fill+retry -> BAR1 -> sentinel(t+2) -> MFMA ->
// gates -> ts transpose -> vmcnt(0) (drains sentinel) -> BAR2 -> coalesced
// data store (no drain) -> prefetch slot t+1.
// Proofs (R9/R11 verbatim): ordering: sentinel drained before BAR2 < data
// stores => observer of h_{t+1} sees sentinel(t+2) first. Readers-done:
// full h_t observed => all 8 community blocks stored h_t => finished step
// t-1 => finished t-2 reads of h_{t-2} (slot being sentinel'd). Ring R=4.
// Prefetch reads slot t+1 after community sentinel(t+1) was drained (it
// preceded their h_t stores which we validated) => sentinel-or-h_{t+1},
// never stale. (R13 exercised exactly this read.)
// ---------------------------------------------------------------------------

typedef short short8 __attribute__((ext_vector_type(8)));
typedef float f32x4 __attribute__((ext_vector_type(4)));
typedef int int4v __attribute__((ext_vector_type(4)));

#define NB 128
#define NT 512
#define ND 512
#define NH 512
#define NG 1536   // 3H
#define HSLOT (NB * NH)  // shorts per h ring slot (128 KB)

__device__ __forceinline__ unsigned short f2bf(float f) {
  union { float f; unsigned u; } v; v.f = f;
  unsigned r = v.u + 0x7fffu + ((v.u >> 16) & 1u);  // RNE
  return (unsigned short)(r >> 16);
}
__device__ __forceinline__ float bf2f(unsigned short u) {
  union { unsigned u; float f; } v; v.u = ((unsigned)u) << 16; return v.f;
}
__device__ __forceinline__ float sigmoid_f(float x) {
  float e = __builtin_amdgcn_exp2f(-1.4426950408889634f * x);
  return __builtin_amdgcn_rcpf(1.0f + e);
}
__device__ __forceinline__ float tanh_f(float x) {
  float e = __builtin_amdgcn_exp2f(2.8853900817779268f * x);
  return 1.0f - 2.0f * __builtin_amdgcn_rcpf(1.0f + e);
}
__device__ __forceinline__ short8 pack8(float4 a, float4 b) {
  short8 s;
  s[0] = (short)f2bf(a.x); s[1] = (short)f2bf(a.y);
  s[2] = (short)f2bf(a.z); s[3] = (short)f2bf(a.w);
  s[4] = (short)f2bf(b.x); s[5] = (short)f2bf(b.y);
  s[6] = (short)f2bf(b.z); s[7] = (short)f2bf(b.w);
  return s;
}

// issue 4 coherent 16B loads, NO wait (prefetch path)
__device__ __forceinline__ void issue4(const unsigned short* r0,
                                       const unsigned short* r1,
                                       const unsigned short* r2,
                                       const unsigned short* r3,
                                       int4v (&v)[4]) {
  asm volatile(
      "global_load_dwordx4 %0, %4, off sc0 sc1\n\t"
      "global_load_dwordx4 %1, %5, off sc0 sc1\n\t"
      "global_load_dwordx4 %2, %6, off sc0 sc1\n\t"
      "global_load_dwordx4 %3, %7, off sc0 sc1"
      : "=&v"(v[0]), "=&v"(v[1]), "=&v"(v[2]), "=&v"(v[3])
      : "v"(r0), "v"(r1), "v"(r2), "v"(r3) : "memory");
}

// drain all vmem; v passed through so later uses are data-ordered after
// the wait (robust against hoisting, rule #18).
__device__ __forceinline__ void wait4(int4v (&v)[4]) {
  asm volatile("s_waitcnt vmcnt(0)"
               : "+v"(v[0]), "+v"(v[1]), "+v"(v[2]), "+v"(v[3]) :: "memory");
}

__device__ __forceinline__ int4v load16_s(const unsigned short* p) {
  int4v v;
  asm volatile("global_load_dwordx4 %0, %1, off sc0 sc1\n\t"
               "s_waitcnt vmcnt(0)"
               : "=v"(v) : "v"(p) : "memory");
  return v;
}

// coalesced coherent 8B store, NO drain (ordering via sentinel protocol)
__device__ __forceinline__ void store8_nd(unsigned short* p, unsigned long long v) {
  asm volatile("global_store_dwordx2 %0, %1, off sc0 sc1"
               :: "v"(p), "v"(v) : "memory");
}

__device__ __forceinline__ unsigned pkmax(unsigned a, unsigned b) {
  unsigned d;
  asm("v_pk_max_u16 %0, %1, %2" : "=v"(d) : "v"(a), "v"(b));
  return d;
}
__device__ __forceinline__ bool has_sent(int4v v) {
  unsigned m = pkmax(pkmax((unsigned)v[0], (unsigned)v[1]),
                     pkmax((unsigned)v[2], (unsigned)v[3]));
  return ((m & 0xFFFFu) == 0xFFFFu) || ((m >> 16) == 0xFFFFu);
}

// ---------------------------------------------------------------------------
// IG = x @ Wih^T + bias, bf16 out. (unchanged)
// ---------------------------------------------------------------------------
__global__ __launch_bounds__(256) void ig_gemm(
    const float* __restrict__ x, const float* __restrict__ Wih,
    const float* __restrict__ bias, unsigned short* __restrict__ IG) {
  __shared__ unsigned short As[128 * 40];
  __shared__ unsigned short Bs[128 * 40];
  const int tid = threadIdx.x;
  const int bn = blockIdx.x, bm = blockIdx.y;
  const int lane = tid & 63, w = tid >> 6;
  const int wm = w >> 1, wn = w & 1;
  const int l15 = lane & 15, q = lane >> 4;

  f32x4 acc[4][4] = {};

  for (int kt = 0; kt < 16; ++kt) {
    __syncthreads();
#pragma unroll
    for (int j = 0; j < 4; ++j) {
      int fi = tid + 256 * j;
      int row = fi >> 3, kq = fi & 7;
      float4 v = *(const float4*)(x + (size_t)(bm * 128 + row) * ND + kt * 32 + kq * 4);
      ushort4 s = {f2bf(v.x), f2bf(v.y), f2bf(v.z), f2bf(v.w)};
      *(ushort4*)&As[row * 40 + kq * 4] = s;
    }
#pragma unroll
    for (int j = 0; j < 4; ++j) {
      int fi = tid + 256 * j;
      int row = fi >> 3, kq = fi & 7;
      float4 v = *(const float4*)(Wih + (size_t)(bn * 128 + row) * ND + kt * 32 + kq * 4);
      ushort4 s = {f2bf(v.x), f2bf(v.y), f2bf(v.z), f2bf(v.w)};
      *(ushort4*)&Bs[row * 40 + kq * 4] = s;
    }
    __syncthreads();

    short8 af[4], bf[4];
#pragma unroll
    for (int tm = 0; tm < 4; ++tm)
      af[tm] = *(const short8*)&As[(wm * 64 + tm * 16 + l15) * 40 + q * 8];
#pragma unroll
    for (int tn = 0; tn < 4; ++tn)
      bf[tn] = *(const short8*)&Bs[(wn * 64 + tn * 16 + l15) * 40 + q * 8];
#pragma unroll
    for (int tm = 0; tm < 4; ++tm)
#pragma unroll
      for (int tn = 0; tn < 4; ++tn)
        acc[tm][tn] = __builtin_amdgcn_mfma_f32_16x16x32_bf16(af[tm], bf[tn], acc[tm][tn], 0, 0, 0);
  }

#pragma unroll
  for (int tm = 0; tm < 4; ++tm) {
#pragma unroll
    for (int tn = 0; tn < 4; ++tn) {
      int col = bn * 128 + wn * 64 + tn * 16 + l15;
      float bb = bias[col];
#pragma unroll
      for (int i = 0; i < 4; ++i) {
        int row = bm * 128 + wm * 64 + tm * 16 + q * 4 + i;
        IG[(size_t)row * NG + col] = f2bf(acc[tm][tn][i] + bb);
      }
    }
  }
}

// ---------------------------------------------------------------------------
// Persistent GRU recurrence. 64 blocks x 256 threads (4 waves, 1/SIMD).
// block: g = bid&7 (rows g*16..+16), c = bid>>3 (cols c*64..+64).
// wave w: 16 rows x 16 cols at col c*64+w*16. Sentinel ring (R11 placement)
// + prefetch-as-poll + strided fill (R13-proven).
// ---------------------------------------------------------------------------
template <bool USE_IG>
__global__ __launch_bounds__(256, 1) void gru_rec(
    const float* __restrict__ x, const float* __restrict__ Wih,
    const float* __restrict__ Whh, const float* __restrict__ bias,
    const float* __restrict__ bn, const unsigned short* __restrict__ IG,
    unsigned short* __restrict__ hbuf, float* __restrict__ hfin) {
  __shared__ __align__(16) unsigned short hs[16 * 512];  // h_t slab (16 KB)
  __shared__ __align__(16) unsigned short ts[16 * 64];   // store tile (2 KB)

  const int tid = threadIdx.x;
  const int lane = tid & 63;
  const int w = tid >> 6;                  // 0..3
  const int l15 = lane & 15, q = lane >> 4;
  const int bid = blockIdx.x;
  const int g = bid & 7, c = bid >> 3;
  const int col = c * 64 + w * 16 + l15;   // this lane's h column
  const int erow = g * 16 + q * 4;         // C-layout batch row base
  const int mrow = g * 16 + l15;           // A-fragment batch row (!USE_IG)

  // Whh B-fragments: 3 gates x 16 k-chunks (192 regs; 512-reg budget at
  // 1 wave/EU -> no spills)
  short8 bfr[3][16];
#pragma unroll
  for (int gt = 0; gt < 3; ++gt) {
    const float* src = Whh + (size_t)(gt * NH + col) * NH + q * 8;
#pragma unroll
    for (int kk = 0; kk < 16; ++kk) {
      float4 v0 = *(const float4*)(src + kk * 32);
      float4 v1 = *(const float4*)(src + kk * 32 + 4);
      bfr[gt][kk] = pack8(v0, v1);
    }
  }

  float bi_r = 0.f, bi_z = 0.f, bi_n = 0.f;
  if (!USE_IG) {
    bi_r = bias[col];
    bi_z = bias[NH + col];
    bi_n = bias[2 * NH + col];
  }
  const float bnv = bn[col];

  float hreg[4] = {0.f, 0.f, 0.f, 0.f};

  // fill indexing (strided, R13 pattern): thread (frow, j2) owns LDS
  // granules {j2, j2+16, 32+j2, 48+j2}; LDS granule s holds global granule
  // s^(frow&7) (XOR with <8 stays in the aligned-16 stride class).
  const int frow = tid >> 4;          // 0..15
  const int j2 = tid & 15;
  const int fr7 = frow & 7;
  const size_t rowoff = (size_t)(g * 16 + frow) * NH;
  const int e0 = ((j2) ^ fr7) << 3;          // global element offsets
  const int e1 = ((j2 + 16) ^ fr7) << 3;
  const int e2 = ((32 + j2) ^ fr7) << 3;
  const int e3 = ((48 + j2) ^ fr7) << 3;

  // store / sentinel cell: 8B per thread (single producer per cell)
  const int srow = tid >> 4;
  const int scol = (tid & 15) * 4;    // shorts
  const size_t cell_off = (size_t)(g * 16 + srow) * NH + c * 64 + scol;

  // prologue: prefetch slot 0 granules (pre-zeroed = h_0, valid)
  int4v v[4];
  issue4(hbuf + rowoff + e0, hbuf + rowoff + e1,
         hbuf + rowoff + e2, hbuf + rowoff + e3, v);

  for (int t = 0; t < NT; ++t) {
    const unsigned short* hcur = hbuf + (size_t)(t & 3) * HSLOT;
    unsigned short* hnxt  = hbuf + (size_t)((t + 1) & 3) * HSLOT;
    unsigned short* hsent = hbuf + (size_t)((t + 2) & 3) * HSLOT;
    const unsigned short* hrow = hcur + rowoff;

    // IG loads (plain cached; consumed at gates -- latency hidden)
    float igr[4], igz[4], ign[4];
    if (USE_IG) {
#pragma unroll
      for (int i = 0; i < 4; ++i) {
        const size_t base = ((size_t)(erow + i) * NT + t) * NG + col;
        igr[i] = bf2f(IG[base]);
        igz[i] = bf2f(IG[base + NH]);
        ign[i] = bf2f(IG[base + 2 * NH]);
      }
    }

    // complete prefetch; retry sentinel-bearing granules (R11 serial form)
    wait4(v);
    if (t > 0) {
      while (has_sent(v[0])) v[0] = load16_s(hrow + e0);
      while (has_sent(v[1])) v[1] = load16_s(hrow + e1);
      while (has_sent(v[2])) v[2] = load16_s(hrow + e2);
      while (has_sent(v[3])) v[3] = load16_s(hrow + e3);
    }
    // stage to LDS (strided -> 2-way write aliasing only)
    *(int4v*)&hs[frow * 512 + (j2 << 3)] = v[0];
    *(int4v*)&hs[frow * 512 + ((j2 + 16) << 3)] = v[1];
    *(int4v*)&hs[frow * 512 + ((32 + j2) << 3)] = v[2];
    *(int4v*)&hs[frow * 512 + ((48 + j2) << 3)] = v[3];
    __syncthreads();  // BAR1: full h_t validated + staged

    // sentinel slot t+2 (R11 placement: AFTER full validation + barrier).
    // Drained by the vmcnt(0) before BAR2 -> visible before any data store.
    if (t + 2 < NT) store8_nd(hsent + cell_off, 0xFFFFFFFFFFFFFFFFull);

    f32x4 ar = {0.f, 0.f, 0.f, 0.f};
    f32x4 az = {0.f, 0.f, 0.f, 0.f};
    f32x4 an = {0.f, 0.f, 0.f, 0.f};
    f32x4 ai = {0.f, 0.f, 0.f, 0.f};
    const int abase = l15 * 512;
    const int ar7 = (l15 & 7) << 3;
#pragma unroll
    for (int kk = 0; kk < 16; ++kk) {
      short8 afk = *(const short8*)&hs[abase + ((kk * 32 + q * 8) ^ ar7)];
      ar = __builtin_amdgcn_mfma_f32_16x16x32_bf16(afk, bfr[0][kk], ar, 0, 0, 0);
      az = __builtin_amdgcn_mfma_f32_16x16x32_bf16(afk, bfr[1][kk], az, 0, 0, 0);
      an = __builtin_amdgcn_mfma_f32_16x16x32_bf16(afk, bfr[2][kk], an, 0, 0, 0);
      if (!USE_IG) {
        const float* xp = x + ((size_t)mrow * NT + t) * ND + kk * 32 + q * 8;
        short8 xa = pack8(*(const float4*)xp, *(const float4*)(xp + 4));
#pragma unroll
        for (int gt = 0; gt < 3; ++gt) {
          const float* wp = Wih + (size_t)(gt * NH + col) * ND + kk * 32 + q * 8;
          short8 wf = pack8(*(const float4*)wp, *(const float4*)(wp + 4));
          if (gt == 0) ar = __builtin_amdgcn_mfma_f32_16x16x32_bf16(xa, wf, ar, 0, 0, 0);
          if (gt == 1) az = __builtin_amdgcn_mfma_f32_16x16x32_bf16(xa, wf, az, 0, 0, 0);
          if (gt == 2) ai = __builtin_amdgcn_mfma_f32_16x16x32_bf16(xa, wf, ai, 0, 0, 0);
        }
      }
    }

    // gates + h update
    unsigned short sv[4];
#pragma unroll
    for (int i = 0; i < 4; ++i) {
      float xr = USE_IG ? (ar[i] + igr[i]) : (ar[i] + bi_r);
      float xz = USE_IG ? (az[i] + igz[i]) : (az[i] + bi_z);
      float xin = USE_IG ? ign[i] : (ai[i] + bi_n);
      float r = sigmoid_f(xr);
      float z = sigmoid_f(xz);
      float n = tanh_f(xin + r * (an[i] + bnv));
      float hn2 = (1.f - z) * n + z * hreg[i];
      hreg[i] = hn2;
      sv[i] = f2bf(hn2);
      if (t == NT - 1) hfin[(size_t)(erow + i) * NH + col] = hn2;
    }

    if (t != NT - 1) {
      // transpose C-layout -> row-major 16x64 tile in ts
#pragma unroll
      for (int i = 0; i < 4; ++i)
        ts[(q * 4 + i) * 64 + w * 16 + l15] = sv[i];
      // drain my sentinel (issued ~1500cy ago: nearly free), then barrier:
      // ALL sentinels visible + all hs reads done before ANY data store.
      asm volatile("s_waitcnt vmcnt(0)" ::: "memory");
      __syncthreads();  // BAR2
      // coalesced coherent data store, NO drain
      store8_nd(hnxt + cell_off,
                *(const unsigned long long*)&ts[srow * 64 + scol]);
      // prefetch-as-poll: issue next step's granules (slot t+1). Community
      // sentinel(t+1) was drained before their h_t stores (validated above)
      // -> reads return sentinel-or-h_{t+1}, never stale; retry fixes
      // sentinels at the head of step t+1. (R13 exercised this read.)
      issue4(hnxt + rowoff + e0, hnxt + rowoff + e1,
             hnxt + rowoff + e2, hnxt + rowoff + e3, v);
    }
  }
}

// ---------------------------------------------------------------------------
// out = h_T @ Wlin^T + blin (unchanged)
// ---------------------------------------------------------------------------
__global__ __launch_bounds__(256) void final_linear(
    const float* __restrict__ hfin, const float* __restrict__ Wlin,
    const float* __restrict__ blin, float* __restrict__ out) {
  __shared__ float sh[16 * 516];
  const int tid = threadIdx.x;
  const int b0 = blockIdx.y * 16, o0 = blockIdx.x * 16;

  for (int j = tid; j < 16 * 128; j += 256) {
    int row = j >> 7, kq = j & 127;
    *(float4*)&sh[row * 516 + kq * 4] =
        *(const float4*)(hfin + (size_t)(b0 + row) * NH + kq * 4);
  }
  __syncthreads();

  const int bi = tid & 15, oi = tid >> 4;
  const int o = o0 + oi;
  const float4* wp = (const float4*)(Wlin + (size_t)o * NH);
  float4 a4 = {0.f, 0.f, 0.f, 0.f};
  for (int k4 = 0; k4 < 128; ++k4) {
    float4 wv = wp[k4];
    float4 hv = *(const float4*)&sh[bi * 516 + k4 * 4];
    a4.x += wv.x * hv.x; a4.y += wv.y * hv.y;
    a4.z += wv.z * hv.z; a4.w += wv.w * hv.w;
  }
  float v = a4.x + a4.y + a4.z + a4.w + blin[o];
  int b = b0 + bi;
  if (o < 256) out[b * 256 + o] = v;
  else out[32768 + b * 256 + (o - 256)] = v;
}

// ---------------------------------------------------------------------------
extern "C" void kernel_launch(void* const* d_in, const int* in_sizes, int n_in,
                              void* d_out, int out_size, void* d_ws, size_t ws_size,
                              hipStream_t stream) {
  const float* x    = (const float*)d_in[0];
  const float* Wih  = (const float*)d_in[1];
  const float* Whh  = (const float*)d_in[2];
  const float* bias = (const float*)d_in[3];
  const float* bn   = (const float*)d_in[4];
  const float* Wlin = (const float*)d_in[5];
  const float* blin = (const float*)d_in[6];
  float* out = (float*)d_out;

  char* ws = (char*)d_ws;
  // layout: [h ring 4*131072][hfin 262144][IG 201326592]
  unsigned short* hbuf = (unsigned short*)ws;
  float* hfin          = (float*)(ws + 4 * 131072);
  unsigned short* IG   = (unsigned short*)(ws + 4 * 131072 + 262144);
  const size_t need_min = 4 * 131072 + 262144;                  // 786432
  const size_t need_ig  = need_min + (size_t)NB * NT * NG * 2;  // ~202 MB
  if (ws_size < need_min) return;

  // slot0 = h_0 = 0; slots 1..3 = 0xFFFF sentinel (graph-capture-safe)
  hipMemsetAsync(ws, 0, 131072, stream);
  hipMemsetAsync(ws + 131072, 0xFF, 3 * 131072, stream);

  const bool useIG = (ws_size >= need_ig);
  if (useIG) {
    ig_gemm<<<dim3(12, 512), 256, 0, stream>>>(x, Wih, bias, IG);
    gru_rec<true><<<64, 256, 0, stream>>>(x, Wih, Whh, bias, bn, IG, hbuf, hfin);
  } else {
    gru_rec<false><<<64, 256, 0, stream>>>(x, Wih, Whh, bias, bn, nullptr, hbuf, hfin);
  }
  final_linear<<<dim3(32, 8), 256, 0, stream>>>(hfin, Wlin, blin, out);
}

// Round 13
// 1976.953 us; speedup vs baseline: 3.8136x; 1.0420x over previous
//
#include <hip/hip_runtime.h>
#include <stdint.h>

// ---------------------------------------------------------------------------
// GRU encoder (B=128,T=512,D=512,H=512,L=256), MI355X gfx950.
//
// R17 = R16's gru_rec VERBATIM (proven, 1648us) + ig_gemm overhaul:
//   ig_gemm was ~360us for 103 GFLOP (~286 TF) -- its K-loop staged fp32->
//   bf16 inline (2048 float4 loads + 8192 f2bf VALU per tile). Now:
//   - cvt_bf16 pass converts x (134MB fp32 -> 67MB bf16) and Wih once
//     (~35us streaming, RNE identical to before => same numerics).
//   - ig_gemm_bf16: staging loop = 2 coalesced short8 loads + 16B LDS
//     stores per thread per matrix; no conversions in the K-loop.
//   Fallback: if workspace < need_bf, run the old fp32-staging ig_gemm.
// ---------------------------------------------------------------------------

typedef short short8 __attribute__((ext_vector_type(8)));
typedef float f32x4 __attribute__((ext_vector_type(4)));
typedef int int4v __attribute__((ext_vector_type(4)));

#define NB 128
#define NT 512
#define ND 512
#define NH 512
#define NG 1536   // 3H
#define HSLOT (NB * NH)  // shorts per h ring slot (128 KB)

__device__ __forceinline__ unsigned short f2bf(float f) {
  union { float f; unsigned u; } v; v.f = f;
  unsigned r = v.u + 0x7fffu + ((v.u >> 16) & 1u);  // RNE
  return (unsigned short)(r >> 16);
}
__device__ __forceinline__ float bf2f(unsigned short u) {
  union { unsigned u; float f; } v; v.u = ((unsigned)u) << 16; return v.f;
}
__device__ __forceinline__ float sigmoid_f(float x) {
  float e = __builtin_amdgcn_exp2f(-1.4426950408889634f * x);
  return __builtin_amdgcn_rcpf(1.0f + e);
}
__device__ __forceinline__ float tanh_f(float x) {
  float e = __builtin_amdgcn_exp2f(2.8853900817779268f * x);
  return 1.0f - 2.0f * __builtin_amdgcn_rcpf(1.0f + e);
}
__device__ __forceinline__ short8 pack8(float4 a, float4 b) {
  short8 s;
  s[0] = (short)f2bf(a.x); s[1] = (short)f2bf(a.y);
  s[2] = (short)f2bf(a.z); s[3] = (short)f2bf(a.w);
  s[4] = (short)f2bf(b.x); s[5] = (short)f2bf(b.y);
  s[6] = (short)f2bf(b.z); s[7] = (short)f2bf(b.w);
  return s;
}

// issue 4 coherent 16B loads, NO wait (prefetch path)
__device__ __forceinline__ void issue4(const unsigned short* r0,
                                       const unsigned short* r1,
                                       const unsigned short* r2,
                                       const unsigned short* r3,
                                       int4v (&v)[4]) {
  asm volatile(
      "global_load_dwordx4 %0, %4, off sc0 sc1\n\t"
      "global_load_dwordx4 %1, %5, off sc0 sc1\n\t"
      "global_load_dwordx4 %2, %6, off sc0 sc1\n\t"
      "global_load_dwordx4 %3, %7, off sc0 sc1"
      : "=&v"(v[0]), "=&v"(v[1]), "=&v"(v[2]), "=&v"(v[3])
      : "v"(r0), "v"(r1), "v"(r2), "v"(r3) : "memory");
}

// drain all vmem; v passed through so later uses are data-ordered after
// the wait (robust against hoisting, rule #18).
__device__ __forceinline__ void wait4(int4v (&v)[4]) {
  asm volatile("s_waitcnt vmcnt(0)"
               : "+v"(v[0]), "+v"(v[1]), "+v"(v[2]), "+v"(v[3]) :: "memory");
}

__device__ __forceinline__ int4v load16_s(const unsigned short* p) {
  int4v v;
  asm volatile("global_load_dwordx4 %0, %1, off sc0 sc1\n\t"
               "s_waitcnt vmcnt(0)"
               : "=v"(v) : "v"(p) : "memory");
  return v;
}

// coalesced coherent 8B store, NO drain (ordering via sentinel protocol)
__device__ __forceinline__ void store8_nd(unsigned short* p, unsigned long long v) {
  asm volatile("global_store_dwordx2 %0, %1, off sc0 sc1"
               :: "v"(p), "v"(v) : "memory");
}

__device__ __forceinline__ unsigned pkmax(unsigned a, unsigned b) {
  unsigned d;
  asm("v_pk_max_u16 %0, %1, %2" : "=v"(d) : "v"(a), "v"(b));
  return d;
}
__device__ __forceinline__ bool has_sent(int4v v) {
  unsigned m = pkmax(pkmax((unsigned)v[0], (unsigned)v[1]),
                     pkmax((unsigned)v[2], (unsigned)v[3]));
  return ((m & 0xFFFFu) == 0xFFFFu) || ((m >> 16) == 0xFFFFu);
}

// ---------------------------------------------------------------------------
// Streaming fp32 -> bf16 convert (RNE, identical to inline f2bf).
// n8 = element count / 8.
// ---------------------------------------------------------------------------
__global__ __launch_bounds__(256) void cvt_bf16(
    const float* __restrict__ in, unsigned short* __restrict__ out, int n8) {
  int i = blockIdx.x * blockDim.x + threadIdx.x;
  const int stride = gridDim.x * blockDim.x;
  for (; i < n8; i += stride) {
    float4 a = ((const float4*)in)[2 * i];
    float4 b = ((const float4*)in)[2 * i + 1];
    *(short8*)&out[(size_t)i * 8] = pack8(a, b);
  }
}

// ---------------------------------------------------------------------------
// IG = x @ Wih^T + bias, bf16 out. M=65536, N=1536, K=512.
// Legacy fp32-staging path (fallback when ws too small for bf16 inputs).
// ---------------------------------------------------------------------------
__global__ __launch_bounds__(256) void ig_gemm(
    const float* __restrict__ x, const float* __restrict__ Wih,
    const float* __restrict__ bias, unsigned short* __restrict__ IG) {
  __shared__ unsigned short As[128 * 40];
  __shared__ unsigned short Bs[128 * 40];
  const int tid = threadIdx.x;
  const int bn = blockIdx.x, bm = blockIdx.y;
  const int lane = tid & 63, w = tid >> 6;
  const int wm = w >> 1, wn = w & 1;
  const int l15 = lane & 15, q = lane >> 4;

  f32x4 acc[4][4] = {};

  for (int kt = 0; kt < 16; ++kt) {
    __syncthreads();
#pragma unroll
    for (int j = 0; j < 4; ++j) {
      int fi = tid + 256 * j;
      int row = fi >> 3, kq = fi & 7;
      float4 v = *(const float4*)(x + (size_t)(bm * 128 + row) * ND + kt * 32 + kq * 4);
      ushort4 s = {f2bf(v.x), f2bf(v.y), f2bf(v.z), f2bf(v.w)};
      *(ushort4*)&As[row * 40 + kq * 4] = s;
    }
#pragma unroll
    for (int j = 0; j < 4; ++j) {
      int fi = tid + 256 * j;
      int row = fi >> 3, kq = fi & 7;
      float4 v = *(const float4*)(Wih + (size_t)(bn * 128 + row) * ND + kt * 32 + kq * 4);
      ushort4 s = {f2bf(v.x), f2bf(v.y), f2bf(v.z), f2bf(v.w)};
      *(ushort4*)&Bs[row * 40 + kq * 4] = s;
    }
    __syncthreads();

    short8 af[4], bf[4];
#pragma unroll
    for (int tm = 0; tm < 4; ++tm)
      af[tm] = *(const short8*)&As[(wm * 64 + tm * 16 + l15) * 40 + q * 8];
#pragma unroll
    for (int tn = 0; tn < 4; ++tn)
      bf[tn] = *(const short8*)&Bs[(wn * 64 + tn * 16 + l15) * 40 + q * 8];
#pragma unroll
    for (int tm = 0; tm < 4; ++tm)
#pragma unroll
      for (int tn = 0; tn < 4; ++tn)
        acc[tm][tn] = __builtin_amdgcn_mfma_f32_16x16x32_bf16(af[tm], bf[tn], acc[tm][tn], 0, 0, 0);
  }

#pragma unroll
  for (int tm = 0; tm < 4; ++tm) {
#pragma unroll
    for (int tn = 0; tn < 4; ++tn) {
      int col = bn * 128 + wn * 64 + tn * 16 + l15;
      float bb = bias[col];
#pragma unroll
      for (int i = 0; i < 4; ++i) {
        int row = bm * 128 + wm * 64 + tm * 16 + q * 4 + i;
        IG[(size_t)row * NG + col] = f2bf(acc[tm][tn][i] + bb);
      }
    }
  }
}

// ---------------------------------------------------------------------------
// ig_gemm with pre-converted bf16 inputs: staging = pure 16B copies
// (2 short8 loads + 2 LDS 16B stores per thread per matrix per tile).
// ---------------------------------------------------------------------------
__global__ __launch_bounds__(256) void ig_gemm_bf16(
    const unsigned short* __restrict__ xb, const unsigned short* __restrict__ wb,
    const float* __restrict__ bias, unsigned short* __restrict__ IG) {
  __shared__ unsigned short As[128 * 40];
  __shared__ unsigned short Bs[128 * 40];
  const int tid = threadIdx.x;
  const int bn = blockIdx.x, bm = blockIdx.y;
  const int lane = tid & 63, w = tid >> 6;
  const int wm = w >> 1, wn = w & 1;
  const int l15 = lane & 15, q = lane >> 4;

  f32x4 acc[4][4] = {};

  for (int kt = 0; kt < 16; ++kt) {
    __syncthreads();
#pragma unroll
    for (int j = 0; j < 2; ++j) {
      int gi = tid + 256 * j;            // 512 granules of 8 elems
      int row = gi >> 2, kq = gi & 3;    // 4 granules per 32-col row
      *(short8*)&As[row * 40 + kq * 8] =
          *(const short8*)(xb + (size_t)(bm * 128 + row) * ND + kt * 32 + kq * 8);
    }
#pragma unroll
    for (int j = 0; j < 2; ++j) {
      int gi = tid + 256 * j;
      int row = gi >> 2, kq = gi & 3;
      *(short8*)&Bs[row * 40 + kq * 8] =
          *(const short8*)(wb + (size_t)(bn * 128 + row) * ND + kt * 32 + kq * 8);
    }
    __syncthreads();

    short8 af[4], bf[4];
#pragma unroll
    for (int tm = 0; tm < 4; ++tm)
      af[tm] = *(const short8*)&As[(wm * 64 + tm * 16 + l15) * 40 + q * 8];
#pragma unroll
    for (int tn = 0; tn < 4; ++tn)
      bf[tn] = *(const short8*)&Bs[(wn * 64 + tn * 16 + l15) * 40 + q * 8];
#pragma unroll
    for (int tm = 0; tm < 4; ++tm)
#pragma unroll
      for (int tn = 0; tn < 4; ++tn)
        acc[tm][tn] = __builtin_amdgcn_mfma_f32_16x16x32_bf16(af[tm], bf[tn], acc[tm][tn], 0, 0, 0);
  }

#pragma unroll
  for (int tm = 0; tm < 4; ++tm) {
#pragma unroll
    for (int tn = 0; tn < 4; ++tn) {
      int col = bn * 128 + wn * 64 + tn * 16 + l15;
      float bb = bias[col];
#pragma unroll
      for (int i = 0; i < 4; ++i) {
        int row = bm * 128 + wm * 64 + tm * 16 + q * 4 + i;
        IG[(size_t)row * NG + col] = f2bf(acc[tm][tn][i] + bb);
      }
    }
  }
}

// ---------------------------------------------------------------------------
// Persistent GRU recurrence. R16 VERBATIM (proven). 64 blocks x 256 thr.
// block: g = bid&7 (rows g*16..+16), c = bid>>3 (cols c*64..+64).
// Sentinel ring (R11 placement) + prefetch-as-poll + strided fill.
// ---------------------------------------------------------------------------
template <bool USE_IG>
__global__ __launch_bounds__(256, 1) void gru_rec(
    const float* __restrict__ x, const float* __restrict__ Wih,
    const float* __restrict__ Whh, const float* __restrict__ bias,
    const float* __restrict__ bn, const unsigned short* __restrict__ IG,
    unsigned short* __restrict__ hbuf, float* __restrict__ hfin) {
  __shared__ __align__(16) unsigned short hs[16 * 512];  // h_t slab (16 KB)
  __shared__ __align__(16) unsigned short ts[16 * 64];   // store tile (2 KB)

  const int tid = threadIdx.x;
  const int lane = tid & 63;
  const int w = tid >> 6;                  // 0..3
  const int l15 = lane & 15, q = lane >> 4;
  const int bid = blockIdx.x;
  const int g = bid & 7, c = bid >> 3;
  const int col = c * 64 + w * 16 + l15;   // this lane's h column
  const int erow = g * 16 + q * 4;         // C-layout batch row base
  const int mrow = g * 16 + l15;           // A-fragment batch row (!USE_IG)

  short8 bfr[3][16];
#pragma unroll
  for (int gt = 0; gt < 3; ++gt) {
    const float* src = Whh + (size_t)(gt * NH + col) * NH + q * 8;
#pragma unroll
    for (int kk = 0; kk < 16; ++kk) {
      float4 v0 = *(const float4*)(src + kk * 32);
      float4 v1 = *(const float4*)(src + kk * 32 + 4);
      bfr[gt][kk] = pack8(v0, v1);
    }
  }

  float bi_r = 0.f, bi_z = 0.f, bi_n = 0.f;
  if (!USE_IG) {
    bi_r = bias[col];
    bi_z = bias[NH + col];
    bi_n = bias[2 * NH + col];
  }
  const float bnv = bn[col];

  float hreg[4] = {0.f, 0.f, 0.f, 0.f};

  const int frow = tid >> 4;          // 0..15
  const int j2 = tid & 15;
  const int fr7 = frow & 7;
  const size_t rowoff = (size_t)(g * 16 + frow) * NH;
  const int e0 = ((j2) ^ fr7) << 3;
  const int e1 = ((j2 + 16) ^ fr7) << 3;
  const int e2 = ((32 + j2) ^ fr7) << 3;
  const int e3 = ((48 + j2) ^ fr7) << 3;

  const int srow = tid >> 4;
  const int scol = (tid & 15) * 4;
  const size_t cell_off = (size_t)(g * 16 + srow) * NH + c * 64 + scol;

  int4v v[4];
  issue4(hbuf + rowoff + e0, hbuf + rowoff + e1,
         hbuf + rowoff + e2, hbuf + rowoff + e3, v);

  for (int t = 0; t < NT; ++t) {
    unsigned short* hnxt  = hbuf + (size_t)((t + 1) & 3) * HSLOT;
    unsigned short* hsent = hbuf + (size_t)((t + 2) & 3) * HSLOT;
    const unsigned short* hrow = hbuf + (size_t)(t & 3) * HSLOT + rowoff;

    float igr[4], igz[4], ign[4];
    if (USE_IG) {
#pragma unroll
      for (int i = 0; i < 4; ++i) {
        const size_t base = ((size_t)(erow + i) * NT + t) * NG + col;
        igr[i] = bf2f(IG[base]);
        igz[i] = bf2f(IG[base + NH]);
        ign[i] = bf2f(IG[base + 2 * NH]);
      }
    }

    wait4(v);
    if (t > 0) {
      while (has_sent(v[0])) v[0] = load16_s(hrow + e0);
      while (has_sent(v[1])) v[1] = load16_s(hrow + e1);
      while (has_sent(v[2])) v[2] = load16_s(hrow + e2);
      while (has_sent(v[3])) v[3] = load16_s(hrow + e3);
    }
    *(int4v*)&hs[frow * 512 + (j2 << 3)] = v[0];
    *(int4v*)&hs[frow * 512 + ((j2 + 16) << 3)] = v[1];
    *(int4v*)&hs[frow * 512 + ((32 + j2) << 3)] = v[2];
    *(int4v*)&hs[frow * 512 + ((48 + j2) << 3)] = v[3];
    __syncthreads();  // BAR1: full h_t validated + staged

    if (t + 2 < NT) store8_nd(hsent + cell_off, 0xFFFFFFFFFFFFFFFFull);

    f32x4 ar = {0.f, 0.f, 0.f, 0.f};
    f32x4 az = {0.f, 0.f, 0.f, 0.f};
    f32x4 an = {0.f, 0.f, 0.f, 0.f};
    f32x4 ai = {0.f, 0.f, 0.f, 0.f};
    const int abase = l15 * 512;
    const int ar7 = (l15 & 7) << 3;
#pragma unroll
    for (int kk = 0; kk < 16; ++kk) {
      short8 afk = *(const short8*)&hs[abase + ((kk * 32 + q * 8) ^ ar7)];
      ar = __builtin_amdgcn_mfma_f32_16x16x32_bf16(afk, bfr[0][kk], ar, 0, 0, 0);
      az = __builtin_amdgcn_mfma_f32_16x16x32_bf16(afk, bfr[1][kk], az, 0, 0, 0);
      an = __builtin_amdgcn_mfma_f32_16x16x32_bf16(afk, bfr[2][kk], an, 0, 0, 0);
      if (!USE_IG) {
        const float* xp = x + ((size_t)mrow * NT + t) * ND + kk * 32 + q * 8;
        short8 xa = pack8(*(const float4*)xp, *(const float4*)(xp + 4));
#pragma unroll
        for (int gt = 0; gt < 3; ++gt) {
          const float* wp = Wih + (size_t)(gt * NH + col) * ND + kk * 32 + q * 8;
          short8 wf = pack8(*(const float4*)wp, *(const float4*)(wp + 4));
          if (gt == 0) ar = __builtin_amdgcn_mfma_f32_16x16x32_bf16(xa, wf, ar, 0, 0, 0);
          if (gt == 1) az = __builtin_amdgcn_mfma_f32_16x16x32_bf16(xa, wf, az, 0, 0, 0);
          if (gt == 2) ai = __builtin_amdgcn_mfma_f32_16x16x32_bf16(xa, wf, ai, 0, 0, 0);
        }
      }
    }

    unsigned short sv[4];
#pragma unroll
    for (int i = 0; i < 4; ++i) {
      float xr = USE_IG ? (ar[i] + igr[i]) : (ar[i] + bi_r);
      float xz = USE_IG ? (az[i] + igz[i]) : (az[i] + bi_z);
      float xin = USE_IG ? ign[i] : (ai[i] + bi_n);
      float r = sigmoid_f(xr);
      float z = sigmoid_f(xz);
      float n = tanh_f(xin + r * (an[i] + bnv));
      float hn2 = (1.f - z) * n + z * hreg[i];
      hreg[i] = hn2;
      sv[i] = f2bf(hn2);
      if (t == NT - 1) hfin[(size_t)(erow + i) * NH + col] = hn2;
    }

    if (t != NT - 1) {
#pragma unroll
      for (int i = 0; i < 4; ++i)
        ts[(q * 4 + i) * 64 + w * 16 + l15] = sv[i];
      asm volatile("s_waitcnt vmcnt(0)" ::: "memory");
      __syncthreads();  // BAR2
      store8_nd(hnxt + cell_off,
                *(const unsigned long long*)&ts[srow * 64 + scol]);
      issue4(hnxt + rowoff + e0, hnxt + rowoff + e1,
             hnxt + rowoff + e2, hnxt + rowoff + e3, v);
    }
  }
}

// ---------------------------------------------------------------------------
// out = h_T @ Wlin^T + blin (unchanged)
// ---------------------------------------------------------------------------
__global__ __launch_bounds__(256) void final_linear(
    const float* __restrict__ hfin, const float* __restrict__ Wlin,
    const float* __restrict__ blin, float* __restrict__ out) {
  __shared__ float sh[16 * 516];
  const int tid = threadIdx.x;
  const int b0 = blockIdx.y * 16, o0 = blockIdx.x * 16;

  for (int j = tid; j < 16 * 128; j += 256) {
    int row = j >> 7, kq = j & 127;
    *(float4*)&sh[row * 516 + kq * 4] =
        *(const float4*)(hfin + (size_t)(b0 + row) * NH + kq * 4);
  }
  __syncthreads();

  const int bi = tid & 15, oi = tid >> 4;
  const int o = o0 + oi;
  const float4* wp = (const float4*)(Wlin + (size_t)o * NH);
  float4 a4 = {0.f, 0.f, 0.f, 0.f};
  for (int k4 = 0; k4 < 128; ++k4) {
    float4 wv = wp[k4];
    float4 hv = *(const float4*)&sh[bi * 516 + k4 * 4];
    a4.x += wv.x * hv.x; a4.y += wv.y * hv.y;
    a4.z += wv.z * hv.z; a4.w += wv.w * hv.w;
  }
  float v = a4.x + a4.y + a4.z + a4.w + blin[o];
  int b = b0 + bi;
  if (o < 256) out[b * 256 + o] = v;
  else out[32768 + b * 256 + (o - 256)] = v;
}

// ---------------------------------------------------------------------------
extern "C" void kernel_launch(void* const* d_in, const int* in_sizes, int n_in,
                              void* d_out, int out_size, void* d_ws, size_t ws_size,
                              hipStream_t stream) {
  const float* x    = (const float*)d_in[0];
  const float* Wih  = (const float*)d_in[1];
  const float* Whh  = (const float*)d_in[2];
  const float* bias = (const float*)d_in[3];
  const float* bn   = (const float*)d_in[4];
  const float* Wlin = (const float*)d_in[5];
  const float* blin = (const float*)d_in[6];
  float* out = (float*)d_out;

  char* ws = (char*)d_ws;
  // layout: [h ring 4*131072][hfin 262144][IG 201326592][xb 67108864][wb 1572864]
  unsigned short* hbuf = (unsigned short*)ws;
  float* hfin          = (float*)(ws + 4 * 131072);
  unsigned short* IG   = (unsigned short*)(ws + 4 * 131072 + 262144);
  const size_t need_min = 4 * 131072 + 262144;                   // 786432
  const size_t need_ig  = need_min + (size_t)NB * NT * NG * 2;   // ~202 MB
  const size_t need_bf  = need_ig + 67108864ull + 1572864ull;    // ~271 MB
  unsigned short* xb = (unsigned short*)(ws + need_ig);
  unsigned short* wb = (unsigned short*)(ws + need_ig + 67108864ull);
  if (ws_size < need_min) return;

  // slot0 = h_0 = 0; slots 1..3 = 0xFFFF sentinel (graph-capture-safe)
  hipMemsetAsync(ws, 0, 131072, stream);
  hipMemsetAsync(ws + 131072, 0xFF, 3 * 131072, stream);

  const bool useIG = (ws_size >= need_ig);
  const bool useBF = (ws_size >= need_bf);
  if (useIG) {
    if (useBF) {
      cvt_bf16<<<2048, 256, 0, stream>>>(x, xb, (NB * NT * ND) / 8);      // 4194304
      cvt_bf16<<<384, 256, 0, stream>>>(Wih, wb, (NG * ND) / 8);          // 98304
      ig_gemm_bf16<<<dim3(12, 512), 256, 0, stream>>>(xb, wb, bias, IG);
    } else {
      ig_gemm<<<dim3(12, 512), 256, 0, stream>>>(x, Wih, bias, IG);
    }
    gru_rec<true><<<64, 256, 0, stream>>>(x, Wih, Whh, bias, bn, IG, hbuf, hfin);
  } else {
    gru_rec<false><<<64, 256, 0, stream>>>(x, Wih, Whh, bias, bn, nullptr, hbuf, hfin);
  }
  final_linear<<<dim3(32, 8), 256, 0, stream>>>(hfin, Wlin, blin, out);
}